// Round 5
// baseline (442.839 us; speedup 1.0000x reference)
//
#include <hip/hip_runtime.h>

// ExternalNeighbors: per-pair displacement + periodic shift + cutoff mask.
// Outputs (concatenated flat, all float32):
//   [0N..1N) dist | [1N..2N) pair_first | [2N..3N) pair_second
//   [3N..6N) paircoord (N,3) | [6N..7N) mask
//
// Round-4 diagnosis: even gather-free extrapolation sits at ~165us vs 64us
// streaming floor -> the 400MB of once-touched streams thrash L2 (32MB),
// evicting the 2MB gather table to L3. Fix: nontemporal loads/stores on all
// streams (nt flag on dwordx4), plain cached access only for the table.

typedef float f32x4 __attribute__((ext_vector_type(4)));
typedef int   i32x4 __attribute__((ext_vector_type(4)));

#define HARD_DIST_CUTOFF 2.0f

__global__ __launch_bounds__(256) void build_gather_table(
    const float* __restrict__ coords,      // n_real * 3
    const int*   __restrict__ real_atoms,  // n_real
    f32x4* __restrict__ tab,               // n_real (padded xyz_)
    int n_real)
{
    const int i = blockIdx.x * blockDim.x + threadIdx.x;
    if (i < n_real) {
        const int a = __builtin_nontemporal_load(real_atoms + i);
        const float* c = coords + 3 * (size_t)a;
        f32x4 v;
        v.x = c[0]; v.y = c[1]; v.z = c[2]; v.w = 0.0f;
        tab[i] = v;  // plain store: keep table L2-resident for the gathers
    }
}

__global__ __launch_bounds__(256, 8) void external_neighbors_v4(
    const f32x4* __restrict__ tab,          // n_real pre-gathered coords
    const int*   __restrict__ shifts,       // n_pairs * 3
    const float* __restrict__ cell,         // 9
    const int*   __restrict__ pair_first,   // n_pairs
    const int*   __restrict__ pair_second,  // n_pairs
    float* __restrict__ out,
    int n_pairs)
{
    const float c00 = cell[0], c01 = cell[1], c02 = cell[2];
    const float c10 = cell[3], c11 = cell[4], c12 = cell[5];
    const float c20 = cell[6], c21 = cell[7], c22 = cell[8];

    const size_t N = (size_t)n_pairs;
    float* __restrict__ out_dist = out;
    float* __restrict__ out_pf   = out + N;
    float* __restrict__ out_ps   = out + 2 * N;
    float* __restrict__ out_pc   = out + 3 * N;
    float* __restrict__ out_mask = out + 6 * N;

    const int tid    = blockIdx.x * blockDim.x + threadIdx.x;
    const int nthr   = gridDim.x * blockDim.x;
    const int nbatch = n_pairs >> 2;  // batches of 4 pairs

    for (int b = tid; b < nbatch; b += nthr) {
        const int base = b << 2;

        // ---- nontemporal stream loads (once-touched; don't pollute L2) ----
        const i32x4 pf4 = __builtin_nontemporal_load(
            reinterpret_cast<const i32x4*>(pair_first + base));
        const i32x4 ps4 = __builtin_nontemporal_load(
            reinterpret_cast<const i32x4*>(pair_second + base));
        const i32x4* sh = reinterpret_cast<const i32x4*>(shifts + 3 * (size_t)base);
        const i32x4 sA = __builtin_nontemporal_load(sh + 0);
        const i32x4 sB = __builtin_nontemporal_load(sh + 1);
        const i32x4 sC = __builtin_nontemporal_load(sh + 2);

        const int pf[4] = {pf4.x, pf4.y, pf4.z, pf4.w};
        const int ps[4] = {ps4.x, ps4.y, ps4.z, ps4.w};
        const int s0[4] = {sA.x, sA.w, sB.z, sC.y};
        const int s1[4] = {sA.y, sB.x, sB.w, sC.z};
        const int s2[4] = {sA.z, sB.y, sC.x, sC.w};

        // ---- 8 independent 16B gathers, plain loads (L2-resident table) ----
        f32x4 A[4], B[4];
        #pragma unroll
        for (int k = 0; k < 4; ++k) A[k] = tab[pf[k]];
        #pragma unroll
        for (int k = 0; k < 4; ++k) B[k] = tab[ps[k]];

        // ---- compute ----
        f32x4 dist, pfo, pso, msk;
        float dxv[4], dyv[4], dzv[4];
        #pragma unroll
        for (int k = 0; k < 4; ++k) {
            const float f0 = (float)s0[k], f1 = (float)s1[k], f2 = (float)s2[k];
            const float dx = B[k].x - A[k].x + f0 * c00 + f1 * c10 + f2 * c20;
            const float dy = B[k].y - A[k].y + f0 * c01 + f1 * c11 + f2 * c21;
            const float dz = B[k].z - A[k].z + f0 * c02 + f1 * c12 + f2 * c22;
            const float d  = sqrtf(dx * dx + dy * dy + dz * dz);
            const bool  m  = d < HARD_DIST_CUTOFF;
            dist[k] = m ? d : 0.0f;
            pfo[k]  = m ? (float)pf[k] : -1.0f;
            pso[k]  = m ? (float)ps[k] : -1.0f;
            msk[k]  = m ? 1.0f : 0.0f;
            dxv[k]  = m ? dx : 0.0f;
            dyv[k]  = m ? dy : 0.0f;
            dzv[k]  = m ? dz : 0.0f;
        }

        // ---- nontemporal vector stores ----
        __builtin_nontemporal_store(dist, reinterpret_cast<f32x4*>(out_dist + base));
        __builtin_nontemporal_store(pfo,  reinterpret_cast<f32x4*>(out_pf   + base));
        __builtin_nontemporal_store(pso,  reinterpret_cast<f32x4*>(out_ps   + base));
        __builtin_nontemporal_store(msk,  reinterpret_cast<f32x4*>(out_mask + base));
        f32x4* pc = reinterpret_cast<f32x4*>(out_pc + 3 * (size_t)base);
        const f32x4 p0 = {dxv[0], dyv[0], dzv[0], dxv[1]};
        const f32x4 p1 = {dyv[1], dzv[1], dxv[2], dyv[2]};
        const f32x4 p2 = {dzv[2], dxv[3], dyv[3], dzv[3]};
        __builtin_nontemporal_store(p0, pc + 0);
        __builtin_nontemporal_store(p1, pc + 1);
        __builtin_nontemporal_store(p2, pc + 2);
    }

    // tail (n_pairs % 4 != 0): scalar fallback
    for (int p = (nbatch << 2) + tid; p < n_pairs; p += nthr) {
        const int pfs = pair_first[p];
        const int pss = pair_second[p];
        const float f0 = (float)shifts[3 * p + 0];
        const float f1 = (float)shifts[3 * p + 1];
        const float f2 = (float)shifts[3 * p + 2];
        const f32x4 Aa = tab[pfs];
        const f32x4 Bb = tab[pss];
        const float dx = Bb.x - Aa.x + f0 * c00 + f1 * c10 + f2 * c20;
        const float dy = Bb.y - Aa.y + f0 * c01 + f1 * c11 + f2 * c21;
        const float dz = Bb.z - Aa.z + f0 * c02 + f1 * c12 + f2 * c22;
        const float d  = sqrtf(dx * dx + dy * dy + dz * dz);
        const bool  m  = d < HARD_DIST_CUTOFF;
        out_dist[p] = m ? d : 0.0f;
        out_pf[p]   = m ? (float)pfs : -1.0f;
        out_ps[p]   = m ? (float)pss : -1.0f;
        out_pc[3*(size_t)p+0] = m ? dx : 0.0f;
        out_pc[3*(size_t)p+1] = m ? dy : 0.0f;
        out_pc[3*(size_t)p+2] = m ? dz : 0.0f;
        out_mask[p] = m ? 1.0f : 0.0f;
    }
}

// Fallback (ws too small): two-hop scalar kernel.
__global__ __launch_bounds__(256) void external_neighbors_v2(
    const float* __restrict__ coords,
    const int*   __restrict__ real_atoms,
    const int*   __restrict__ shifts,
    const float* __restrict__ cell,
    const int*   __restrict__ pair_first,
    const int*   __restrict__ pair_second,
    float* __restrict__ out,
    int n_pairs)
{
    const float c00 = cell[0], c01 = cell[1], c02 = cell[2];
    const float c10 = cell[3], c11 = cell[4], c12 = cell[5];
    const float c20 = cell[6], c21 = cell[7], c22 = cell[8];
    const size_t N = (size_t)n_pairs;
    float* out_dist = out;
    float* out_pf   = out + N;
    float* out_ps   = out + 2 * N;
    float* out_pc   = out + 3 * N;
    float* out_mask = out + 6 * N;
    const int tid = blockIdx.x * blockDim.x + threadIdx.x;
    const int stride = gridDim.x * blockDim.x;
    for (int p = tid; p < n_pairs; p += stride) {
        const int pfs = pair_first[p];
        const int pss = pair_second[p];
        const float f0 = (float)shifts[3 * p + 0];
        const float f1 = (float)shifts[3 * p + 1];
        const float f2 = (float)shifts[3 * p + 2];
        const int iaa = real_atoms[pfs];
        const int ibb = real_atoms[pss];
        const float dx = coords[3*ibb+0] - coords[3*iaa+0] + f0*c00 + f1*c10 + f2*c20;
        const float dy = coords[3*ibb+1] - coords[3*iaa+1] + f0*c01 + f1*c11 + f2*c21;
        const float dz = coords[3*ibb+2] - coords[3*iaa+2] + f0*c02 + f1*c12 + f2*c22;
        const float d  = sqrtf(dx*dx + dy*dy + dz*dz);
        const bool  m  = d < HARD_DIST_CUTOFF;
        out_dist[p] = m ? d : 0.0f;
        out_pf[p]   = m ? (float)pfs : -1.0f;
        out_ps[p]   = m ? (float)pss : -1.0f;
        out_pc[3*(size_t)p+0] = m ? dx : 0.0f;
        out_pc[3*(size_t)p+1] = m ? dy : 0.0f;
        out_pc[3*(size_t)p+2] = m ? dz : 0.0f;
        out_mask[p] = m ? 1.0f : 0.0f;
    }
}

extern "C" void kernel_launch(void* const* d_in, const int* in_sizes, int n_in,
                              void* d_out, int out_size, void* d_ws, size_t ws_size,
                              hipStream_t stream) {
    const float* coords      = (const float*)d_in[0];  // (128,1024,3) f32
    const int*   real_atoms  = (const int*)d_in[1];    // (131072,) int
    const int*   shifts      = (const int*)d_in[2];    // (8388608,3) int
    const float* cell        = (const float*)d_in[3];  // (3,3) f32
    const int*   pair_first  = (const int*)d_in[4];    // (8388608,) int
    const int*   pair_second = (const int*)d_in[5];    // (8388608,) int
    float*       out         = (float*)d_out;

    const int n_real  = in_sizes[1];  // 131072
    const int n_pairs = in_sizes[4];  // 8388608

    const size_t tab_bytes = (size_t)n_real * sizeof(f32x4);

    if (ws_size >= tab_bytes) {
        f32x4* tab = (f32x4*)d_ws;
        build_gather_table<<<(n_real + 255) / 256, 256, 0, stream>>>(
            coords, real_atoms, tab, n_real);

        // 2048 persistent blocks: 8 wg/CU, exactly 4 batches/thread at 8.39M pairs
        external_neighbors_v4<<<2048, 256, 0, stream>>>(
            tab, shifts, cell, pair_first, pair_second, out, n_pairs);
    } else {
        external_neighbors_v2<<<2048, 256, 0, stream>>>(
            coords, real_atoms, shifts, cell, pair_first, pair_second, out, n_pairs);
    }
}